// Round 3
// baseline (284345.679 us; speedup 1.0000x reference)
//
#include <hip/hip_runtime.h>
#include <cstddef>

#define T_STEPS 4096
#define H_DIM   4096
#define IN_DIM  1024
#define O_DIM   512

__device__ __forceinline__ float sigmoid_f(float v) {
    v = fminf(fmaxf(v, -30.f), 30.f);
    return 1.f / (1.f + __expf(-v));
}
__device__ __forceinline__ float tanh_f(float v) {
    v = fminf(fmaxf(v, -15.f), 15.f);
    float e = __expf(2.f * v);
    return (e - 1.f) / (e + 1.f);
}

// Persistent cooperative kernel: 256 WGs (1/CU) x 1024 threads (16 waves,
// 4 waves/EU). Each WAVE owns one row of W_rec (64 floats/lane = 64 VGPR)
// and one row of W_in (16 VGPR); each WG owns 2 rows of W_out (8 VGPR).
// Total ~88 weight VGPRs + working set fits the 128-VGPR budget that
// 4 waves/EU implies -- R1/R2 showed the allocator refuses to go past 128
// regardless of launch_bounds/waves_per_eu, spilling the old 2-rows-per-wave
// layout to scratch (566 MB FETCH, 40 us/step). Weight "arrays" are
// individually named registers (macros) so SROA can't demote them.
__global__ __launch_bounds__(1024, 4) void snn_persistent(
    const float* __restrict__ x, const float* __restrict__ Win,
    const float* __restrict__ Wrec, const float* __restrict__ Wout,
    const float* __restrict__ gbias, float* __restrict__ y,
    float* __restrict__ hbuf, unsigned int* __restrict__ flags)
{
    __shared__ __attribute__((aligned(16))) float h_lds[H_DIM];   // 16 KB
    __shared__ __attribute__((aligned(16))) float x_lds[IN_DIM];  // 4 KB
    __shared__ float osc[16][2];

    const int tid = threadIdx.x;
    const int w   = tid >> 6;     // wave 0..15
    const int l   = tid & 63;     // lane
    const int wg  = blockIdx.x;   // 0..255

    const int row   = wg * 16 + w;   // the hidden row this wave owns
    const int orow0 = wg * 2;        // output rows this WG owns
    const int orow1 = orow0 + 1;

    // ---- one-time weight load into named registers (coalesced float4) ----
    const float4* pw = (const float4*)Wrec + (size_t)row * (H_DIM / 4) + l;
#define WRL(k) const float4 wr##k = pw[(k) * 64];
    WRL(0) WRL(1) WRL(2) WRL(3) WRL(4) WRL(5) WRL(6) WRL(7)
    WRL(8) WRL(9) WRL(10) WRL(11) WRL(12) WRL(13) WRL(14) WRL(15)
#undef WRL

    const float4* pi = (const float4*)Win + (size_t)row * (IN_DIM / 4) + l;
    const float4 wi0 = pi[0 * 64];
    const float4 wi1 = pi[1 * 64];
    const float4 wi2 = pi[2 * 64];
    const float4 wi3 = pi[3 * 64];

    const float* po0 = Wout + (size_t)orow0 * H_DIM + tid;
    const float* po1 = Wout + (size_t)orow1 * H_DIM + tid;
    const float wo00 = po0[0], wo01 = po0[1024], wo02 = po0[2048], wo03 = po0[3072];
    const float wo10 = po1[0], wo11 = po1[1024], wo12 = po1[2048], wo13 = po1[3072];

    const float gb   = gbias[row];
    const float leak = 0.1f;

    float* buf0 = hbuf;          // h_t for even t (zeroed by host memset for t=0)
    float* buf1 = hbuf + H_DIM;  // h_t for odd t

    #pragma unroll 1
    for (int t = 0; t <= T_STEPS; ++t) {
        float* cur = (t & 1) ? buf1 : buf0;
        float* nxt = (t & 1) ? buf0 : buf1;

        // stage h_t (and x_t) into LDS: 1024 threads x one float4 each
        ((float4*)h_lds)[tid] = ((const float4*)cur)[tid];
        if (t < T_STEPS && tid < 256) {
            ((float4*)x_lds)[tid] = ((const float4*)(x + (size_t)t * IN_DIM))[tid];
        }
        __syncthreads();

        // ---- y[t-1] = W_out . h_t (block-wide split dot over 2 rows) ----
        if (t >= 1) {
            float p0 = fmaf(wo00, h_lds[tid],        fmaf(wo01, h_lds[tid + 1024],
                       fmaf(wo02, h_lds[tid + 2048],      wo03 * h_lds[tid + 3072])));
            float p1 = fmaf(wo10, h_lds[tid],        fmaf(wo11, h_lds[tid + 1024],
                       fmaf(wo12, h_lds[tid + 2048],      wo13 * h_lds[tid + 3072])));
            #pragma unroll
            for (int off = 32; off; off >>= 1) {
                p0 += __shfl_xor(p0, off);
                p1 += __shfl_xor(p1, off);
            }
            if (l == 0) { osc[w][0] = p0; osc[w][1] = p1; }
        }
        if (t == T_STEPS) {  // epilogue: only the final y remains
            __syncthreads();
            if (tid == 0) {
                float s0 = 0.f, s1 = 0.f;
                #pragma unroll
                for (int q = 0; q < 16; ++q) { s0 += osc[q][0]; s1 += osc[q][1]; }
                y[(size_t)(T_STEPS - 1) * O_DIM + orow0] = s0;
                y[(size_t)(T_STEPS - 1) * O_DIM + orow1] = s1;
            }
            break;
        }

        // ---- r[row] = W_rec row . h_t (named registers x LDS) ----
        float4 a = make_float4(0.f, 0.f, 0.f, 0.f);
        {
            const float4* h4 = (const float4*)h_lds;
#define WRF(k) { float4 hv = h4[(k) * 64 + l];              \
                 a.x = fmaf(wr##k.x, hv.x, a.x);            \
                 a.y = fmaf(wr##k.y, hv.y, a.y);            \
                 a.z = fmaf(wr##k.z, hv.z, a.z);            \
                 a.w = fmaf(wr##k.w, hv.w, a.w); }
            WRF(0) WRF(1) WRF(2) WRF(3) WRF(4) WRF(5) WRF(6) WRF(7)
            WRF(8) WRF(9) WRF(10) WRF(11) WRF(12) WRF(13) WRF(14) WRF(15)
#undef WRF
        }
        // ---- i[row] = W_in row . x_t ----
        float4 b = make_float4(0.f, 0.f, 0.f, 0.f);
        {
            const float4* x4 = (const float4*)x_lds;
#define WIF(k, wv) { float4 xv = x4[(k) * 64 + l];          \
                     b.x = fmaf(wv.x, xv.x, b.x);           \
                     b.y = fmaf(wv.y, xv.y, b.y);           \
                     b.z = fmaf(wv.z, xv.z, b.z);           \
                     b.w = fmaf(wv.w, xv.w, b.w); }
            WIF(0, wi0) WIF(1, wi1) WIF(2, wi2) WIF(3, wi3)
#undef WIF
        }
        float r = (a.x + a.y) + (a.z + a.w);
        float i = (b.x + b.y) + (b.z + b.w);
        #pragma unroll
        for (int off = 32; off; off >>= 1) {
            r += __shfl_xor(r, off);
            i += __shfl_xor(i, off);
        }
        if (l == 0) {
            float g  = sigmoid_f(gb + r);
            float z  = tanh_f(fmaf(g, r, i));
            float h0 = h_lds[row];
            nxt[row] = fmaf(leak, z - h0, h0);
        }
        __syncthreads();  // all waves' h stores drained (vmcnt) + osc visible

        // ---- grid barrier (generation t+1) ----
        if (tid == 0) {
            if (t >= 1) {
                float s0 = 0.f, s1 = 0.f;
                #pragma unroll
                for (int q = 0; q < 16; ++q) { s0 += osc[q][0]; s1 += osc[q][1]; }
                y[(size_t)(t - 1) * O_DIM + orow0] = s0;
                y[(size_t)(t - 1) * O_DIM + orow1] = s1;
            }
            __threadfence();  // L2 writeback: h_{t+1} visible device-wide
            __hip_atomic_store(&flags[wg], (unsigned)(t + 1),
                               __ATOMIC_RELAXED, __HIP_MEMORY_SCOPE_AGENT);
        }
        if (tid < 256) {
            const unsigned tgt = (unsigned)(t + 1);
            while (__hip_atomic_load(&flags[tid], __ATOMIC_RELAXED,
                                     __HIP_MEMORY_SCOPE_AGENT) < tgt) {}
        }
        __threadfence();  // invalidate stale caches before reading new h
        __syncthreads();
    }
}

extern "C" void kernel_launch(void* const* d_in, const int* in_sizes, int n_in,
                              void* d_out, int out_size, void* d_ws, size_t ws_size,
                              hipStream_t stream) {
    const float* x     = (const float*)d_in[0];
    const float* Win   = (const float*)d_in[1];
    const float* Wrec  = (const float*)d_in[2];
    const float* Wout  = (const float*)d_in[3];
    const float* gbias = (const float*)d_in[4];
    float* y = (float*)d_out;

    float* hbuf = (float*)d_ws;                                    // 2 x 4096 fp32
    unsigned int* flags = (unsigned int*)((char*)d_ws + 2 * H_DIM * sizeof(float));

    // ws is re-poisoned to 0xAA before every replay: zero h0 + flags each call.
    hipMemsetAsync(d_ws, 0, 2 * H_DIM * sizeof(float) + 256 * sizeof(unsigned int),
                   stream);

    void* args[] = { (void*)&x, (void*)&Win, (void*)&Wrec, (void*)&Wout,
                     (void*)&gbias, (void*)&y, (void*)&hbuf, (void*)&flags };
    hipLaunchCooperativeKernel((const void*)snn_persistent, dim3(256), dim3(1024),
                               args, 0, stream);
}

// Round 4
// 280335.229 us; speedup vs baseline: 1.0143x; 1.0143x over previous
//
#include <hip/hip_runtime.h>
#include <cstddef>

#define T_STEPS 4096
#define H_DIM   4096
#define IN_DIM  1024
#define O_DIM   512

__device__ __forceinline__ float sigmoid_f(float v) {
    v = fminf(fmaxf(v, -30.f), 30.f);
    return 1.f / (1.f + __expf(-v));
}
__device__ __forceinline__ float tanh_f(float v) {
    v = fminf(fmaxf(v, -15.f), 15.f);
    float e = __expf(2.f * v);
    return (e - 1.f) / (e + 1.f);
}

// Force a value to stay in a VGPR: after this, the value is defined by the
// asm (opaque), so the scheduler cannot re-materialize the original global
// load inside the loop. R1-R3 disasm-level evidence: the compiler sank the
// loop-invariant weight loads into the t-loop (VGPR_Count 64-128, ~84 MB of
// L2/L3 weight re-reads per step, 40-70 us/step).
#define PIN4(v) asm volatile("" : "+v"(v.x), "+v"(v.y), "+v"(v.z), "+v"(v.w))
#define PIN1(v) asm volatile("" : "+v"(v))

// Persistent cooperative kernel: 256 WGs (1/CU) x 1024 threads (16 waves,
// 4 waves/EU exact). Each WAVE owns one row of W_rec (64 floats/lane =
// 64 VGPR) + one row of W_in (16 VGPR); each WG owns 2 rows of W_out
// (8 VGPR/thread). ~110 VGPR demand < 128 budget at 4 waves/EU.
__global__
__attribute__((amdgpu_flat_work_group_size(1024, 1024), amdgpu_waves_per_eu(4, 4)))
void snn_persistent(
    const float* __restrict__ x, const float* __restrict__ Win,
    const float* __restrict__ Wrec, const float* __restrict__ Wout,
    const float* __restrict__ gbias, float* __restrict__ y,
    float* __restrict__ hbuf, unsigned int* __restrict__ flags)
{
    __shared__ __attribute__((aligned(16))) float h_lds[H_DIM];   // 16 KB
    __shared__ __attribute__((aligned(16))) float x_lds[IN_DIM];  // 4 KB
    __shared__ float osc[16][2];

    const int tid = threadIdx.x;
    const int w   = tid >> 6;     // wave 0..15
    const int l   = tid & 63;     // lane
    const int wg  = blockIdx.x;   // 0..255

    const int row   = wg * 16 + w;   // the hidden row this wave owns
    const int orow0 = wg * 2;        // output rows this WG owns
    const int orow1 = orow0 + 1;

    // ---- one-time weight load into pinned registers (coalesced float4) ----
    const float4* pw = (const float4*)Wrec + (size_t)row * (H_DIM / 4) + l;
#define WRL(k) float4 wr##k = pw[(k) * 64]; PIN4(wr##k);
    WRL(0) WRL(1) WRL(2) WRL(3) WRL(4) WRL(5) WRL(6) WRL(7)
    WRL(8) WRL(9) WRL(10) WRL(11) WRL(12) WRL(13) WRL(14) WRL(15)
#undef WRL

    const float4* pi = (const float4*)Win + (size_t)row * (IN_DIM / 4) + l;
    float4 wi0 = pi[0 * 64]; PIN4(wi0);
    float4 wi1 = pi[1 * 64]; PIN4(wi1);
    float4 wi2 = pi[2 * 64]; PIN4(wi2);
    float4 wi3 = pi[3 * 64]; PIN4(wi3);

    const float* po0 = Wout + (size_t)orow0 * H_DIM + tid;
    const float* po1 = Wout + (size_t)orow1 * H_DIM + tid;
    float wo00 = po0[0], wo01 = po0[1024], wo02 = po0[2048], wo03 = po0[3072];
    float wo10 = po1[0], wo11 = po1[1024], wo12 = po1[2048], wo13 = po1[3072];
    PIN1(wo00); PIN1(wo01); PIN1(wo02); PIN1(wo03);
    PIN1(wo10); PIN1(wo11); PIN1(wo12); PIN1(wo13);

    const float gb   = gbias[row];
    const float leak = 0.1f;

    float* buf0 = hbuf;          // h_t for even t (zeroed by host memset for t=0)
    float* buf1 = hbuf + H_DIM;  // h_t for odd t

    #pragma unroll 1
    for (int t = 0; t <= T_STEPS; ++t) {
        float* cur = (t & 1) ? buf1 : buf0;
        float* nxt = (t & 1) ? buf0 : buf1;

        // stage h_t (and x_t) into LDS: 1024 threads x one float4 each
        ((float4*)h_lds)[tid] = ((const float4*)cur)[tid];
        if (t < T_STEPS && tid < 256) {
            ((float4*)x_lds)[tid] = ((const float4*)(x + (size_t)t * IN_DIM))[tid];
        }
        __syncthreads();

        // ---- y[t-1] = W_out . h_t (block-wide split dot over 2 rows) ----
        if (t >= 1) {
            float p0 = fmaf(wo00, h_lds[tid],        fmaf(wo01, h_lds[tid + 1024],
                       fmaf(wo02, h_lds[tid + 2048],      wo03 * h_lds[tid + 3072])));
            float p1 = fmaf(wo10, h_lds[tid],        fmaf(wo11, h_lds[tid + 1024],
                       fmaf(wo12, h_lds[tid + 2048],      wo13 * h_lds[tid + 3072])));
            #pragma unroll
            for (int off = 32; off; off >>= 1) {
                p0 += __shfl_xor(p0, off);
                p1 += __shfl_xor(p1, off);
            }
            if (l == 0) { osc[w][0] = p0; osc[w][1] = p1; }
        }
        if (t == T_STEPS) {  // epilogue: only the final y remains
            __syncthreads();
            if (tid == 0) {
                float s0 = 0.f, s1 = 0.f;
                #pragma unroll
                for (int q = 0; q < 16; ++q) { s0 += osc[q][0]; s1 += osc[q][1]; }
                y[(size_t)(T_STEPS - 1) * O_DIM + orow0] = s0;
                y[(size_t)(T_STEPS - 1) * O_DIM + orow1] = s1;
            }
            break;
        }

        // ---- r[row] = W_rec row . h_t (pinned registers x LDS) ----
        float4 a = make_float4(0.f, 0.f, 0.f, 0.f);
        {
            const float4* h4 = (const float4*)h_lds;
#define WRF(k) { float4 hv = h4[(k) * 64 + l];              \
                 a.x = fmaf(wr##k.x, hv.x, a.x);            \
                 a.y = fmaf(wr##k.y, hv.y, a.y);            \
                 a.z = fmaf(wr##k.z, hv.z, a.z);            \
                 a.w = fmaf(wr##k.w, hv.w, a.w); }
            WRF(0) WRF(1) WRF(2) WRF(3) WRF(4) WRF(5) WRF(6) WRF(7)
            WRF(8) WRF(9) WRF(10) WRF(11) WRF(12) WRF(13) WRF(14) WRF(15)
#undef WRF
        }
        // ---- i[row] = W_in row . x_t ----
        float4 b = make_float4(0.f, 0.f, 0.f, 0.f);
        {
            const float4* x4 = (const float4*)x_lds;
#define WIF(k, wv) { float4 xv = x4[(k) * 64 + l];          \
                     b.x = fmaf(wv.x, xv.x, b.x);           \
                     b.y = fmaf(wv.y, xv.y, b.y);           \
                     b.z = fmaf(wv.z, xv.z, b.z);           \
                     b.w = fmaf(wv.w, xv.w, b.w); }
            WIF(0, wi0) WIF(1, wi1) WIF(2, wi2) WIF(3, wi3)
#undef WIF
        }
        float r = (a.x + a.y) + (a.z + a.w);
        float i = (b.x + b.y) + (b.z + b.w);
        #pragma unroll
        for (int off = 32; off; off >>= 1) {
            r += __shfl_xor(r, off);
            i += __shfl_xor(i, off);
        }
        if (l == 0) {
            float g  = sigmoid_f(gb + r);
            float z  = tanh_f(fmaf(g, r, i));
            float h0 = h_lds[row];
            nxt[row] = fmaf(leak, z - h0, h0);
        }
        __syncthreads();  // all waves' h stores drained (vmcnt) + osc visible

        // ---- grid barrier (generation t+1) ----
        if (tid == 0) {
            if (t >= 1) {
                float s0 = 0.f, s1 = 0.f;
                #pragma unroll
                for (int q = 0; q < 16; ++q) { s0 += osc[q][0]; s1 += osc[q][1]; }
                y[(size_t)(t - 1) * O_DIM + orow0] = s0;
                y[(size_t)(t - 1) * O_DIM + orow1] = s1;
            }
            __threadfence();  // L2 writeback: h_{t+1} visible device-wide
            __hip_atomic_store(&flags[wg], (unsigned)(t + 1),
                               __ATOMIC_RELAXED, __HIP_MEMORY_SCOPE_AGENT);
        }
        if (tid < 256) {
            const unsigned tgt = (unsigned)(t + 1);
            while (__hip_atomic_load(&flags[tid], __ATOMIC_RELAXED,
                                     __HIP_MEMORY_SCOPE_AGENT) < tgt) {}
        }
        __threadfence();  // invalidate stale caches before reading new h
        __syncthreads();
    }
}

extern "C" void kernel_launch(void* const* d_in, const int* in_sizes, int n_in,
                              void* d_out, int out_size, void* d_ws, size_t ws_size,
                              hipStream_t stream) {
    const float* x     = (const float*)d_in[0];
    const float* Win   = (const float*)d_in[1];
    const float* Wrec  = (const float*)d_in[2];
    const float* Wout  = (const float*)d_in[3];
    const float* gbias = (const float*)d_in[4];
    float* y = (float*)d_out;

    float* hbuf = (float*)d_ws;                                    // 2 x 4096 fp32
    unsigned int* flags = (unsigned int*)((char*)d_ws + 2 * H_DIM * sizeof(float));

    // ws is re-poisoned to 0xAA before every replay: zero h0 + flags each call.
    hipMemsetAsync(d_ws, 0, 2 * H_DIM * sizeof(float) + 256 * sizeof(unsigned int),
                   stream);

    void* args[] = { (void*)&x, (void*)&Win, (void*)&Wrec, (void*)&Wout,
                     (void*)&gbias, (void*)&y, (void*)&hbuf, (void*)&flags };
    hipLaunchCooperativeKernel((const void*)snn_persistent, dim3(256), dim3(1024),
                               args, 0, stream);
}

// Round 6
// 169656.360 us; speedup vs baseline: 1.6760x; 1.6524x over previous
//
#include <hip/hip_runtime.h>
#include <cstddef>

#define T_STEPS 4096
#define H_DIM   4096
#define IN_DIM  1024
#define O_DIM   512
#define N_WG    256   // 1 block/CU -- launch shape proven in R1/R2

__device__ __forceinline__ float sigmoid_f(float v) {
    v = fminf(fmaxf(v, -30.f), 30.f);
    return 1.f / (1.f + __expf(-v));
}
__device__ __forceinline__ float tanh_f(float v) {
    v = fminf(fmaxf(v, -15.f), 15.f);
    float e = __expf(2.f * v);
    return (e - 1.f) / (e + 1.f);
}

// Keep W_rec register-row values opaque so the scheduler can't sink/remat the
// global loads into the t-loop (R3: remat = 84 MB/step L2 re-reads; R4:
// pin+overbudget = scratch spills). Here demand fits the 128-VGPR grant.
#define PIN4(v) asm volatile("" : "+v"(v.x), "+v"(v.y), "+v"(v.z), "+v"(v.w))

// fp32 -> packed bf16x2 (round-to-nearest-even), and unpack helpers.
__device__ __forceinline__ unsigned pack_bf2(float a, float b) {
    unsigned ua = __float_as_uint(a), ub = __float_as_uint(b);
    ua = (ua + 0x7fffu + ((ua >> 16) & 1u)) >> 16;
    ub = (ub + 0x7fffu + ((ub >> 16) & 1u)) & 0xffff0000u;
    return ua | ub;
}
__device__ __forceinline__ float bf_lo(unsigned u) { return __uint_as_float(u << 16); }
__device__ __forceinline__ float bf_hi(unsigned u) { return __uint_as_float(u & 0xffff0000u); }

// Persistent cooperative kernel: 256 WGs (1/CU) x 512 threads (8 waves).
// W_rec split: 8 rows/WG in registers (1 row/wave = 64 VGPR, fits the 128
// grant R1/R2 demonstrated) + 8 rows/WG in LDS fp32 (128 KB of the 160 KB
// CU budget). W_in / W_out live in registers as packed bf16 (linear taps,
// ~1e-3 error vs 1.6e-2 threshold; recurrence-critical W_rec stays fp32).
__global__ __launch_bounds__(512, 2) void snn_persistent(
    const float* __restrict__ x, const float* __restrict__ Win,
    const float* __restrict__ Wrec, const float* __restrict__ Wout,
    const float* __restrict__ gbias, float* __restrict__ y,
    float* __restrict__ hbuf, unsigned int* __restrict__ flags)
{
    __shared__ __attribute__((aligned(16))) float w_lds[8 * H_DIM];  // 128 KB
    __shared__ __attribute__((aligned(16))) float h_lds[H_DIM];      // 16 KB
    __shared__ __attribute__((aligned(16))) float x_lds[IN_DIM];     // 4 KB
    __shared__ float osc[8][2];

    const int tid = threadIdx.x;
    const int w   = tid >> 6;     // wave 0..7
    const int l   = tid & 63;     // lane
    const int wg  = blockIdx.x;   // 0..255

    const int rowA  = wg * 16 + w;      // register-resident W_rec row
    const int rowB  = wg * 16 + 8 + w;  // LDS-resident W_rec row
    const int orow0 = wg * 2;           // output rows this WG owns
    const int orow1 = orow0 + 1;

    // ---- one-time: reg row A (pinned), LDS row B, bf16 W_in/W_out ----
    const float4* pa = (const float4*)Wrec + (size_t)rowA * (H_DIM / 4) + l;
#define WRL(k) float4 wr##k = pa[(k) * 64]; PIN4(wr##k);
    WRL(0) WRL(1) WRL(2) WRL(3) WRL(4) WRL(5) WRL(6) WRL(7)
    WRL(8) WRL(9) WRL(10) WRL(11) WRL(12) WRL(13) WRL(14) WRL(15)
#undef WRL

    {
        const float4* pb = (const float4*)Wrec + (size_t)rowB * (H_DIM / 4) + l;
        float4* wl4 = (float4*)(w_lds + (size_t)w * H_DIM);
        #pragma unroll
        for (int k = 0; k < 16; ++k) wl4[k * 64 + l] = pb[k * 64];
    }

    const float4* pia = (const float4*)Win + (size_t)rowA * (IN_DIM / 4) + l;
    const float4* pib = (const float4*)Win + (size_t)rowB * (IN_DIM / 4) + l;
    unsigned wiA[8], wiB[8];
    #pragma unroll
    for (int k = 0; k < 4; ++k) {
        float4 va = pia[k * 64], vb = pib[k * 64];
        wiA[2 * k]     = pack_bf2(va.x, va.y);
        wiA[2 * k + 1] = pack_bf2(va.z, va.w);
        wiB[2 * k]     = pack_bf2(vb.x, vb.y);
        wiB[2 * k + 1] = pack_bf2(vb.z, vb.w);
    }

    const float* po0 = Wout + (size_t)orow0 * H_DIM + tid;
    const float* po1 = Wout + (size_t)orow1 * H_DIM + tid;
    unsigned woP0[4], woP1[4];
    #pragma unroll
    for (int j = 0; j < 4; ++j) {
        woP0[j] = pack_bf2(po0[1024 * j], po0[1024 * j + 512]);
        woP1[j] = pack_bf2(po1[1024 * j], po1[1024 * j + 512]);
    }

    const float gbA  = gbias[rowA];
    const float gbB  = gbias[rowB];
    const float leak = 0.1f;

    float* buf0 = hbuf;          // h_t for even t (zeroed by host memset for t=0)
    float* buf1 = hbuf + H_DIM;  // h_t for odd t

    #pragma unroll 1
    for (int t = 0; t <= T_STEPS; ++t) {
        float* cur = (t & 1) ? buf1 : buf0;
        float* nxt = (t & 1) ? buf0 : buf1;

        // stage h_t (and x_t) into LDS
        {
            const float4* c4 = (const float4*)cur;
            float4* h4 = (float4*)h_lds;
            h4[tid]       = c4[tid];
            h4[tid + 512] = c4[tid + 512];
        }
        if (t < T_STEPS && tid < 256) {
            ((float4*)x_lds)[tid] = ((const float4*)(x + (size_t)t * IN_DIM))[tid];
        }
        __syncthreads();

        // ---- y[t-1] = W_out . h_t (block-wide split dot, bf16 taps) ----
        if (t >= 1) {
            float p0 = 0.f, p1 = 0.f;
            #pragma unroll
            for (int j = 0; j < 4; ++j) {
                float h0 = h_lds[tid + 1024 * j];
                float h1 = h_lds[tid + 1024 * j + 512];
                p0 = fmaf(bf_lo(woP0[j]), h0, fmaf(bf_hi(woP0[j]), h1, p0));
                p1 = fmaf(bf_lo(woP1[j]), h0, fmaf(bf_hi(woP1[j]), h1, p1));
            }
            #pragma unroll
            for (int off = 32; off; off >>= 1) {
                p0 += __shfl_xor(p0, off);
                p1 += __shfl_xor(p1, off);
            }
            if (l == 0) { osc[w][0] = p0; osc[w][1] = p1; }
        }
        if (t == T_STEPS) {  // epilogue: only the final y remains
            __syncthreads();
            if (tid == 0) {
                float s0 = 0.f, s1 = 0.f;
                #pragma unroll
                for (int q = 0; q < 8; ++q) { s0 += osc[q][0]; s1 += osc[q][1]; }
                y[(size_t)(T_STEPS - 1) * O_DIM + orow0] = s0;
                y[(size_t)(T_STEPS - 1) * O_DIM + orow1] = s1;
            }
            break;
        }

        // ---- fused: rA = wr(regs).h , rB = w_lds[w].h  (h read once) ----
        float4 a = make_float4(0.f, 0.f, 0.f, 0.f);
        float4 b = make_float4(0.f, 0.f, 0.f, 0.f);
        {
            const float4* h4  = (const float4*)h_lds;
            const float4* wl4 = (const float4*)(w_lds + (size_t)w * H_DIM);
#define WRF(k) { float4 hv = h4[(k) * 64 + l];              \
                 float4 wv = wl4[(k) * 64 + l];             \
                 a.x = fmaf(wr##k.x, hv.x, a.x);            \
                 a.y = fmaf(wr##k.y, hv.y, a.y);            \
                 a.z = fmaf(wr##k.z, hv.z, a.z);            \
                 a.w = fmaf(wr##k.w, hv.w, a.w);            \
                 b.x = fmaf(wv.x, hv.x, b.x);               \
                 b.y = fmaf(wv.y, hv.y, b.y);               \
                 b.z = fmaf(wv.z, hv.z, b.z);               \
                 b.w = fmaf(wv.w, hv.w, b.w); }
            WRF(0) WRF(1) WRF(2) WRF(3) WRF(4) WRF(5) WRF(6) WRF(7)
            WRF(8) WRF(9) WRF(10) WRF(11) WRF(12) WRF(13) WRF(14) WRF(15)
#undef WRF
        }
        // ---- iA/iB = W_in rows . x_t (bf16 taps) ----
        float iA = 0.f, iB = 0.f;
        {
            const float4* x4 = (const float4*)x_lds;
            #pragma unroll
            for (int k = 0; k < 4; ++k) {
                float4 xv = x4[k * 64 + l];
                unsigned a0 = wiA[2 * k], a1 = wiA[2 * k + 1];
                unsigned b0 = wiB[2 * k], b1 = wiB[2 * k + 1];
                iA = fmaf(bf_lo(a0), xv.x, fmaf(bf_hi(a0), xv.y,
                     fmaf(bf_lo(a1), xv.z, fmaf(bf_hi(a1), xv.w, iA))));
                iB = fmaf(bf_lo(b0), xv.x, fmaf(bf_hi(b0), xv.y,
                     fmaf(bf_lo(b1), xv.z, fmaf(bf_hi(b1), xv.w, iB))));
            }
        }
        float rA = (a.x + a.y) + (a.z + a.w);
        float rB = (b.x + b.y) + (b.z + b.w);
        #pragma unroll
        for (int off = 32; off; off >>= 1) {
            rA += __shfl_xor(rA, off);
            rB += __shfl_xor(rB, off);
            iA += __shfl_xor(iA, off);
            iB += __shfl_xor(iB, off);
        }
        if (l == 0) {
            float gA = sigmoid_f(gbA + rA);
            float zA = tanh_f(fmaf(gA, rA, iA));
            float hA = h_lds[rowA];
            nxt[rowA] = fmaf(leak, zA - hA, hA);
            float gB = sigmoid_f(gbB + rB);
            float zB = tanh_f(fmaf(gB, rB, iB));
            float hB = h_lds[rowB];
            nxt[rowB] = fmaf(leak, zB - hB, hB);
        }
        __syncthreads();  // all waves drain vmcnt (h stores in L2) + osc visible

        // ---- grid barrier (generation t+1) ----
        if (tid == 0) {
            if (t >= 1) {
                float s0 = 0.f, s1 = 0.f;
                #pragma unroll
                for (int q = 0; q < 8; ++q) { s0 += osc[q][0]; s1 += osc[q][1]; }
                y[(size_t)(t - 1) * O_DIM + orow0] = s0;
                y[(size_t)(t - 1) * O_DIM + orow1] = s1;
            }
            __threadfence();  // L2 writeback: h_{t+1} visible device-wide
            __hip_atomic_store(&flags[wg], (unsigned)(t + 1),
                               __ATOMIC_RELAXED, __HIP_MEMORY_SCOPE_AGENT);
        }
        if (tid < N_WG) {
            const unsigned tgt = (unsigned)(t + 1);
            while (__hip_atomic_load(&flags[tid], __ATOMIC_RELAXED,
                                     __HIP_MEMORY_SCOPE_AGENT) < tgt) {}
        }
        __threadfence();  // invalidate stale caches before reading new h
        __syncthreads();
    }
}

extern "C" void kernel_launch(void* const* d_in, const int* in_sizes, int n_in,
                              void* d_out, int out_size, void* d_ws, size_t ws_size,
                              hipStream_t stream) {
    const float* x     = (const float*)d_in[0];
    const float* Win   = (const float*)d_in[1];
    const float* Wrec  = (const float*)d_in[2];
    const float* Wout  = (const float*)d_in[3];
    const float* gbias = (const float*)d_in[4];
    float* y = (float*)d_out;

    float* hbuf = (float*)d_ws;                                    // 2 x 4096 fp32
    unsigned int* flags = (unsigned int*)((char*)d_ws + 2 * H_DIM * sizeof(float));

    // ws is re-poisoned to 0xAA before every replay: zero h0 + flags each call.
    hipMemsetAsync(d_ws, 0,
                   2 * H_DIM * sizeof(float) + N_WG * sizeof(unsigned int), stream);

    void* args[] = { (void*)&x, (void*)&Win, (void*)&Wrec, (void*)&Wout,
                     (void*)&gbias, (void*)&y, (void*)&hbuf, (void*)&flags };
    hipLaunchCooperativeKernel((const void*)snn_persistent, dim3(N_WG), dim3(512),
                               args, 0, stream);
}

// Round 7
// 36007.922 us; speedup vs baseline: 7.8968x; 4.7116x over previous
//
#include <hip/hip_runtime.h>
#include <cstddef>

#define T_STEPS 4096
#define H_DIM   4096
#define IN_DIM  1024
#define O_DIM   512
#define N_WG    256   // 1 block/CU -- launch shape proven in R1/R2/R6

__device__ __forceinline__ float sigmoid_f(float v) {
    v = fminf(fmaxf(v, -30.f), 30.f);
    return 1.f / (1.f + __expf(-v));
}
__device__ __forceinline__ float tanh_f(float v) {
    v = fminf(fmaxf(v, -15.f), 15.f);
    float e = __expf(2.f * v);
    return (e - 1.f) / (e + 1.f);
}

// Keep W_rec register-row values opaque so the scheduler can't sink/remat the
// global loads into the t-loop (R3: remat = 84 MB/step L2 re-reads; R4:
// pin+overbudget = scratch spills). R6 proved demand fits the 128-VGPR grant.
#define PIN4(v) asm volatile("" : "+v"(v.x), "+v"(v.y), "+v"(v.z), "+v"(v.w))

// fp32 -> packed bf16x2 (round-to-nearest-even), and unpack helpers.
__device__ __forceinline__ unsigned pack_bf2(float a, float b) {
    unsigned ua = __float_as_uint(a), ub = __float_as_uint(b);
    ua = (ua + 0x7fffu + ((ua >> 16) & 1u)) >> 16;
    ub = (ub + 0x7fffu + ((ub >> 16) & 1u)) & 0xffff0000u;
    return ua | ub;
}
__device__ __forceinline__ float bf_lo(unsigned u) { return __uint_as_float(u << 16); }
__device__ __forceinline__ float bf_hi(unsigned u) { return __uint_as_float(u & 0xffff0000u); }

// R7: FENCE-FREE grid step. R1-R6 all plateaued at ~40 us/step regardless of
// where the weights lived; the invariant was __threadfence() on both sides of
// the barrier -- on gfx9xx multi-XCD that lowers to buffer_wbl2/buffer_inv
// (full 4 MB L2 walks), ~2300 L2-walk ops per step. Instead: the 4 KB of
// truly shared state (h) travels via relaxed AGENT-scope atomics, which are
// performed at the coherence point (L3) and bypass the non-coherent L2s in
// both directions. Ordering: h-stores drain via the s_waitcnt vmcnt(0) that
// __syncthreads() emits, THEN the generation flag is stored; consumers poll
// the flag, then (compiler barrier only) re-read h with bypassing loads.
__global__ __launch_bounds__(512, 2) void snn_persistent(
    const float* __restrict__ x, const float* __restrict__ Win,
    const float* __restrict__ Wrec, const float* __restrict__ Wout,
    const float* __restrict__ gbias, float* __restrict__ y,
    float* __restrict__ hbuf, unsigned int* __restrict__ flags)
{
    __shared__ __attribute__((aligned(16))) float w_lds[8 * H_DIM];  // 128 KB
    __shared__ __attribute__((aligned(16))) float h_lds[H_DIM];      // 16 KB
    __shared__ __attribute__((aligned(16))) float x_lds[IN_DIM];     // 4 KB
    __shared__ float osc[8][2];

    const int tid = threadIdx.x;
    const int w   = tid >> 6;     // wave 0..7
    const int l   = tid & 63;     // lane
    const int wg  = blockIdx.x;   // 0..255

    const int rowA  = wg * 16 + w;      // register-resident W_rec row
    const int rowB  = wg * 16 + 8 + w;  // LDS-resident W_rec row
    const int orow0 = wg * 2;           // output rows this WG owns
    const int orow1 = orow0 + 1;

    // ---- one-time: reg row A (pinned), LDS row B, bf16 W_in/W_out ----
    const float4* pa = (const float4*)Wrec + (size_t)rowA * (H_DIM / 4) + l;
#define WRL(k) float4 wr##k = pa[(k) * 64]; PIN4(wr##k);
    WRL(0) WRL(1) WRL(2) WRL(3) WRL(4) WRL(5) WRL(6) WRL(7)
    WRL(8) WRL(9) WRL(10) WRL(11) WRL(12) WRL(13) WRL(14) WRL(15)
#undef WRL

    {
        const float4* pb = (const float4*)Wrec + (size_t)rowB * (H_DIM / 4) + l;
        float4* wl4 = (float4*)(w_lds + (size_t)w * H_DIM);
        #pragma unroll
        for (int k = 0; k < 16; ++k) wl4[k * 64 + l] = pb[k * 64];
    }

    const float4* pia = (const float4*)Win + (size_t)rowA * (IN_DIM / 4) + l;
    const float4* pib = (const float4*)Win + (size_t)rowB * (IN_DIM / 4) + l;
    unsigned wiA[8], wiB[8];
    #pragma unroll
    for (int k = 0; k < 4; ++k) {
        float4 va = pia[k * 64], vb = pib[k * 64];
        wiA[2 * k]     = pack_bf2(va.x, va.y);
        wiA[2 * k + 1] = pack_bf2(va.z, va.w);
        wiB[2 * k]     = pack_bf2(vb.x, vb.y);
        wiB[2 * k + 1] = pack_bf2(vb.z, vb.w);
    }

    const float* po0 = Wout + (size_t)orow0 * H_DIM + tid;
    const float* po1 = Wout + (size_t)orow1 * H_DIM + tid;
    unsigned woP0[4], woP1[4];
    #pragma unroll
    for (int j = 0; j < 4; ++j) {
        woP0[j] = pack_bf2(po0[1024 * j], po0[1024 * j + 512]);
        woP1[j] = pack_bf2(po1[1024 * j], po1[1024 * j + 512]);
    }

    const float gbA  = gbias[rowA];
    const float gbB  = gbias[rowB];
    const float leak = 0.1f;

    float* buf0 = hbuf;          // h_t for even t (zeroed by host memset for t=0)
    float* buf1 = hbuf + H_DIM;  // h_t for odd t

    #pragma unroll 1
    for (int t = 0; t <= T_STEPS; ++t) {
        float* cur = (t & 1) ? buf1 : buf0;
        float* nxt = (t & 1) ? buf0 : buf1;

        // stage h_t into LDS via agent-scope (L2-bypassing) loads; x_t via
        // normal cached loads (read-only input, no staleness hazard).
        #pragma unroll
        for (int k = 0; k < 8; ++k) {
            h_lds[tid + k * 512] = __hip_atomic_load(
                &cur[tid + k * 512], __ATOMIC_RELAXED, __HIP_MEMORY_SCOPE_AGENT);
        }
        if (t < T_STEPS && tid < 256) {
            ((float4*)x_lds)[tid] = ((const float4*)(x + (size_t)t * IN_DIM))[tid];
        }
        __syncthreads();

        // ---- y[t-1] = W_out . h_t (block-wide split dot, bf16 taps) ----
        if (t >= 1) {
            float p0 = 0.f, p1 = 0.f;
            #pragma unroll
            for (int j = 0; j < 4; ++j) {
                float h0 = h_lds[tid + 1024 * j];
                float h1 = h_lds[tid + 1024 * j + 512];
                p0 = fmaf(bf_lo(woP0[j]), h0, fmaf(bf_hi(woP0[j]), h1, p0));
                p1 = fmaf(bf_lo(woP1[j]), h0, fmaf(bf_hi(woP1[j]), h1, p1));
            }
            #pragma unroll
            for (int off = 32; off; off >>= 1) {
                p0 += __shfl_xor(p0, off);
                p1 += __shfl_xor(p1, off);
            }
            if (l == 0) { osc[w][0] = p0; osc[w][1] = p1; }
        }
        if (t == T_STEPS) {  // epilogue: only the final y remains
            __syncthreads();
            if (tid == 0) {
                float s0 = 0.f, s1 = 0.f;
                #pragma unroll
                for (int q = 0; q < 8; ++q) { s0 += osc[q][0]; s1 += osc[q][1]; }
                y[(size_t)(T_STEPS - 1) * O_DIM + orow0] = s0;
                y[(size_t)(T_STEPS - 1) * O_DIM + orow1] = s1;
            }
            break;
        }

        // ---- fused: rA = wr(regs).h , rB = w_lds[w].h  (h read once) ----
        float4 a = make_float4(0.f, 0.f, 0.f, 0.f);
        float4 b = make_float4(0.f, 0.f, 0.f, 0.f);
        {
            const float4* h4  = (const float4*)h_lds;
            const float4* wl4 = (const float4*)(w_lds + (size_t)w * H_DIM);
#define WRF(k) { float4 hv = h4[(k) * 64 + l];              \
                 float4 wv = wl4[(k) * 64 + l];             \
                 a.x = fmaf(wr##k.x, hv.x, a.x);            \
                 a.y = fmaf(wr##k.y, hv.y, a.y);            \
                 a.z = fmaf(wr##k.z, hv.z, a.z);            \
                 a.w = fmaf(wr##k.w, hv.w, a.w);            \
                 b.x = fmaf(wv.x, hv.x, b.x);               \
                 b.y = fmaf(wv.y, hv.y, b.y);               \
                 b.z = fmaf(wv.z, hv.z, b.z);               \
                 b.w = fmaf(wv.w, hv.w, b.w); }
            WRF(0) WRF(1) WRF(2) WRF(3) WRF(4) WRF(5) WRF(6) WRF(7)
            WRF(8) WRF(9) WRF(10) WRF(11) WRF(12) WRF(13) WRF(14) WRF(15)
#undef WRF
        }
        // ---- iA/iB = W_in rows . x_t (bf16 taps) ----
        float iA = 0.f, iB = 0.f;
        {
            const float4* x4 = (const float4*)x_lds;
            #pragma unroll
            for (int k = 0; k < 4; ++k) {
                float4 xv = x4[k * 64 + l];
                unsigned a0 = wiA[2 * k], a1 = wiA[2 * k + 1];
                unsigned b0 = wiB[2 * k], b1 = wiB[2 * k + 1];
                iA = fmaf(bf_lo(a0), xv.x, fmaf(bf_hi(a0), xv.y,
                     fmaf(bf_lo(a1), xv.z, fmaf(bf_hi(a1), xv.w, iA))));
                iB = fmaf(bf_lo(b0), xv.x, fmaf(bf_hi(b0), xv.y,
                     fmaf(bf_lo(b1), xv.z, fmaf(bf_hi(b1), xv.w, iB))));
            }
        }
        float rA = (a.x + a.y) + (a.z + a.w);
        float rB = (b.x + b.y) + (b.z + b.w);
        #pragma unroll
        for (int off = 32; off; off >>= 1) {
            rA += __shfl_xor(rA, off);
            rB += __shfl_xor(rB, off);
            iA += __shfl_xor(iA, off);
            iB += __shfl_xor(iB, off);
        }
        if (l == 0) {
            float gA = sigmoid_f(gbA + rA);
            float zA = tanh_f(fmaf(gA, rA, iA));
            float hA = h_lds[rowA];
            __hip_atomic_store(&nxt[rowA], fmaf(leak, zA - hA, hA),
                               __ATOMIC_RELAXED, __HIP_MEMORY_SCOPE_AGENT);
            float gB = sigmoid_f(gbB + rB);
            float zB = tanh_f(fmaf(gB, rB, iB));
            float hB = h_lds[rowB];
            __hip_atomic_store(&nxt[rowB], fmaf(leak, zB - hB, hB),
                               __ATOMIC_RELAXED, __HIP_MEMORY_SCOPE_AGENT);
        }
        // __syncthreads() emits s_waitcnt vmcnt(0) per wave before s_barrier:
        // all h atomic stores are performed at the coherence point after this.
        __syncthreads();

        // ---- fence-free grid barrier (generation t+1) ----
        if (tid == 0) {
            if (t >= 1) {
                float s0 = 0.f, s1 = 0.f;
                #pragma unroll
                for (int q = 0; q < 8; ++q) { s0 += osc[q][0]; s1 += osc[q][1]; }
                y[(size_t)(t - 1) * O_DIM + orow0] = s0;
                y[(size_t)(t - 1) * O_DIM + orow1] = s1;
            }
            __hip_atomic_store(&flags[wg], (unsigned)(t + 1),
                               __ATOMIC_RELAXED, __HIP_MEMORY_SCOPE_AGENT);
        }
        if (tid < N_WG) {
            const unsigned tgt = (unsigned)(t + 1);
            while (__hip_atomic_load(&flags[tid], __ATOMIC_RELAXED,
                                     __HIP_MEMORY_SCOPE_AGENT) < tgt) {}
        }
        asm volatile("" ::: "memory");  // compiler reorder guard (no L2 walk)
        __syncthreads();
    }
}

extern "C" void kernel_launch(void* const* d_in, const int* in_sizes, int n_in,
                              void* d_out, int out_size, void* d_ws, size_t ws_size,
                              hipStream_t stream) {
    const float* x     = (const float*)d_in[0];
    const float* Win   = (const float*)d_in[1];
    const float* Wrec  = (const float*)d_in[2];
    const float* Wout  = (const float*)d_in[3];
    const float* gbias = (const float*)d_in[4];
    float* y = (float*)d_out;

    float* hbuf = (float*)d_ws;                                    // 2 x 4096 fp32
    unsigned int* flags = (unsigned int*)((char*)d_ws + 2 * H_DIM * sizeof(float));

    // ws is re-poisoned to 0xAA before every replay: zero h0 + flags each call.
    hipMemsetAsync(d_ws, 0,
                   2 * H_DIM * sizeof(float) + N_WG * sizeof(unsigned int), stream);

    void* args[] = { (void*)&x, (void*)&Win, (void*)&Wrec, (void*)&Wout,
                     (void*)&gbias, (void*)&y, (void*)&hbuf, (void*)&flags };
    hipLaunchCooperativeKernel((const void*)snn_persistent, dim3(N_WG), dim3(512),
                               args, 0, stream);
}